// Round 2
// baseline (7250.409 us; speedup 1.0000x reference)
//
#include <hip/hip_runtime.h>
#include <math.h>

#define N 4096
#define STEPS 16384
#define CHUNK 16
#define NCHUNK (STEPS / CHUNK)
#define MBLK 1024
#define SST 20   // padded stride (floats) for ST/SX: float4-aligned, 2-way-bank max (free)
#define NW (MBLK - 64)    // 960 worker threads (waves 1..15)
#define XBASE (4 * NW)    // 3840: first 3840 elements owned 4-per-worker
#define NX (N - XBASE)    // 256 extras owned 1-each by tid 64..319

// Workgroup barrier that does NOT drain vmcnt (LDS-only ordering between phases).
__device__ __forceinline__ void lgkm_barrier() {
  asm volatile("s_waitcnt lgkmcnt(0)\n\ts_barrier" ::: "memory");
}

// ---- prep: thr[t] = atanh(2u-1) in fp64; lastocc[t] = no later same-idx in chunk ----
__global__ __launch_bounds__(256) void pre_kernel(const float* __restrict__ u,
                                                  const int* __restrict__ idx,
                                                  double* __restrict__ thr,
                                                  int* __restrict__ lastocc) {
  int t = blockIdx.x * 256 + threadIdx.x;
  if (t < STEPS) {
    float r = 2.0f * u[t] - 1.0f;          // exact same fp32 rounding as reference
    double rd = (double)r;
    thr[t] = 0.5 * log((1.0 + rd) / (1.0 - rd));   // r=-1 -> -inf (tie->+1 matches ref)
    int cbase = t & ~(CHUNK - 1);
    int my = idx[t];
    int lo = 1;
    for (int tt = (t & (CHUNK - 1)) + 1; tt < CHUNK; ++tt)
      if (idx[cbase + tt] == my) { lo = 0; break; }
    lastocc[t] = lo;
  }
}

// ---- initial field: I0[row] = sum_k J[row,k]*m0[k] + h[row], fp64 accumulate ----
__global__ __launch_bounds__(256) void init_field_kernel(const float* __restrict__ J,
                                                         const float* __restrict__ h,
                                                         const float* __restrict__ m0,
                                                         double* __restrict__ I) {
  __shared__ double red[256];
  int row = blockIdx.x;
  const float4* Jr = (const float4*)(J + (size_t)row * N);
  const float4* mv = (const float4*)m0;
  double acc = 0.0;
  for (int q = threadIdx.x; q < N / 4; q += 256) {
    float4 a = Jr[q];
    float4 b = mv[q];
    acc += (double)(a.x * b.x) + (double)(a.y * b.y) +
           (double)(a.z * b.z) + (double)(a.w * b.w);
  }
  red[threadIdx.x] = acc;
  __syncthreads();
  for (int s = 128; s > 0; s >>= 1) {
    if (threadIdx.x < s) red[threadIdx.x] += red[threadIdx.x + s];
    __syncthreads();
  }
  if (threadIdx.x == 0) I[row] = red[0] + (double)h[row];
}

// ---- overlapped chunk-resolved Glauber chain: 1 workgroup, 1024 threads ----
// Phase 1 (concurrent): wave0 (prio 3) resolves chunk k flip-driven, accumulating
//   xacc = cross-corrections J[idx_k][idx_{k+1}] for the next chunk; workers
//   (waves 1-15, prio 0) apply chunk k-1's flips to the full fp64 field.
//   Wave0's phase-1 entry is PURE register/LDS-resident: all global pipeline
//   loads are issued after the resolve (addresses carried one iteration ahead),
//   ST/SX register fragments were prefetched in the previous phase 2.
// Phase 2 (short): wave0 forms chunk-k+1 inputs Ireg = field_lds[idx]+xacc and
//   prefetches ST/SX fragments; workers pre-read chunk k's flip rows+deltas.
// Barriers are lgkm-only; in-flight vmem (gathers) crosses them.
__global__ __launch_bounds__(MBLK) void pbit_kernel(const float* __restrict__ J,
                                                    const float* __restrict__ m0,
                                                    const int* __restrict__ idx,
                                                    const double* __restrict__ thr,
                                                    const int* __restrict__ lastocc,
                                                    const double* __restrict__ I0,
                                                    float* __restrict__ out) {
  __shared__ __align__(16) double field_lds[N];        // 32 KB master field
  __shared__ __align__(16) float m_lds[N];             // 16 KB spins
  __shared__ __align__(16) float ST_lds[CHUNK * SST];  // ST[c*SST+r] = J[idx_k[r]][idx_k[c]]
  __shared__ __align__(16) float SX_lds[CHUNK * SST];  // SX[c*SST+r] = J[idx_k[r]][idx_{k+1}[c]]
  __shared__ __align__(16) int   pubi_lds[2][CHUNK];   // double-buffered flip rows
  __shared__ __align__(16) float pubd_lds[2][CHUNK];   // double-buffered deltas (+/-2)
  __shared__ int pubF_lds[2];                          // flip counts

  const int tid = threadIdx.x;

  // field_lds init by launch layout (independent of apply ownership)
  {
    const double* ip = I0 + 4 * tid;
    double a = ip[0], b = ip[1], c = ip[2], d = ip[3];
    *(double2*)(field_lds + 4 * tid + 0) = make_double2(a, b);
    *(double2*)(field_lds + 4 * tid + 2) = make_double2(c, d);
  }
  ((float4*)m_lds)[tid] = ((const float4*)m0)[tid];
  if (tid == 0) { pubF_lds[0] = 0; pubF_lds[1] = 0; }

  const int t16 = tid & 15;       // step slot within chunk
  const int gt = tid >> 2;        // gather row slot (wave0: 0..15)
  const int gq = (tid & 3) * 4;   // gather col group

  // ---- worker (waves 1-15) field ownership: fp64 registers + LDS write-through ----
  const bool isw = (tid >= 64);
  const int wid = isw ? (tid - 64) : 0;
  const bool isx = isw && (tid < 64 + NX);
  double i0 = 0.0, i1 = 0.0, i2 = 0.0, i3 = 0.0, i4 = 0.0;
  if (isw) {
    const double* ip = I0 + 4 * wid;
    i0 = ip[0]; i1 = ip[1]; i2 = ip[2]; i3 = ip[3];
    if (isx) i4 = I0[XBASE + wid];
  }
  const float* Jb = J + 4 * (size_t)wid;
  const float* Jx = J + XBASE + (size_t)wid;
  int rows[CHUNK];
  float dv[CHUNK];
  int Fprev = 0;

  // ---- wave0 pipeline registers ----
  int mi = 0, ni = 0, mlo = 0, nlo = 0, p2i = 0, p2lo = 0;
  double mt = 0.0, nt = 0.0, p2t = 0.0;
  float fST0 = 0, fST1 = 0, fST2 = 0, fST3 = 0;
  float fSX0 = 0, fSX1 = 0, fSX2 = 0, fSX3 = 0;
  int gArow = 0, gAt0 = 0, gAt1 = 0, gAt2 = 0, gAt3 = 0;
  int gAu0 = 0, gAu1 = 0, gAu2 = 0, gAu3 = 0;
  double Ireg = 0.0, xacc = 0.0;
  float mym = 0.0f;
  float4 sA, sB, sC, sD, xA, xB, xC, xD;   // register ST/SX columns for current chunk
  sA = sB = sC = sD = xA = xB = xC = xD = make_float4(0.f, 0.f, 0.f, 0.f);

  if (tid < 64) {
    __builtin_amdgcn_s_setprio(3);         // protect the serial resolve chain
    mi = idx[t16];       mt = thr[t16];       mlo = lastocc[t16];
    ni = idx[16 + t16];  nt = thr[16 + t16];  nlo = lastocc[16 + t16];
    p2i = idx[32 + t16]; p2t = thr[32 + t16]; p2lo = lastocc[32 + t16];
    // synchronous gather: ST(0)=J[idx0][idx0], SX(0->1)=J[idx0][idx1]
    int r0 = idx[gt];
    int c0 = idx[gq], c1 = idx[gq + 1], c2 = idx[gq + 2], c3 = idx[gq + 3];
    int x0 = idx[16 + gq], x1 = idx[16 + gq + 1], x2 = idx[16 + gq + 2], x3 = idx[16 + gq + 3];
    const float* Jr = J + (size_t)r0 * N;
    ST_lds[(gq + 0) * SST + gt] = Jr[c0];
    ST_lds[(gq + 1) * SST + gt] = Jr[c1];
    ST_lds[(gq + 2) * SST + gt] = Jr[c2];
    ST_lds[(gq + 3) * SST + gt] = Jr[c3];
    SX_lds[(gq + 0) * SST + gt] = Jr[x0];
    SX_lds[(gq + 1) * SST + gt] = Jr[x1];
    SX_lds[(gq + 2) * SST + gt] = Jr[x2];
    SX_lds[(gq + 3) * SST + gt] = Jr[x3];
    // sync gather into regs: fST=ST(1)=J[idx1][idx1], fSX=SX(1->2)=J[idx1][idx2]
    int r1 = idx[16 + gt];
    int y0 = idx[32 + gq], y1 = idx[32 + gq + 1], y2 = idx[32 + gq + 2], y3 = idx[32 + gq + 3];
    const float* Jg = J + (size_t)r1 * N;
    fST0 = Jg[x0]; fST1 = Jg[x1]; fST2 = Jg[x2]; fST3 = Jg[x3];
    fSX0 = Jg[y0]; fSX1 = Jg[y1]; fSX2 = Jg[y2]; fSX3 = Jg[y3];
    // gather-address set for iteration 0 (produces ST(2), SX(2->3))
    gArow = idx[32 + gt];
    gAt0 = y0; gAt1 = y1; gAt2 = y2; gAt3 = y3;
    gAu0 = idx[48 + gq];     gAu1 = idx[48 + gq + 1];
    gAu2 = idx[48 + gq + 2]; gAu3 = idx[48 + gq + 3];
  }
  __syncthreads();
  if (tid < 64) {
    Ireg = field_lds[mi];   // I0 value for chunk 0
    mym = m_lds[mi];
    const float* sp = &ST_lds[t16 * SST];
    sA = *(const float4*)(sp + 0);  sB = *(const float4*)(sp + 4);
    sC = *(const float4*)(sp + 8);  sD = *(const float4*)(sp + 12);
    const float* xp = &SX_lds[t16 * SST];
    xA = *(const float4*)(xp + 0);  xB = *(const float4*)(xp + 4);
    xC = *(const float4*)(xp + 8);  xD = *(const float4*)(xp + 12);
  }

  int cur = 0;
  for (int k = 0; k < NCHUNK; ++k) {
    // ================= Phase 1 (concurrent) =================
    if (isw) {
      // apply chunk k-1's flips (rows[]/dv[]/Fprev preloaded in previous phase 2)
      if (Fprev > 0) {
#pragma unroll
        for (int b = 0; b < CHUNK; b += 8) {
          if (b < Fprev) {                  // uniform
            float4 rr[8];
            float rx[8] = {0, 0, 0, 0, 0, 0, 0, 0};
#pragma unroll
            for (int t = 0; t < 8; ++t)
              if (b + t < Fprev) rr[t] = *(const float4*)(Jb + (size_t)rows[b + t] * N);
            if (isx) {                      // waves 1-4: extra owned element
#pragma unroll
              for (int t = 0; t < 8; ++t)
                if (b + t < Fprev) rx[t] = Jx[(size_t)rows[b + t] * N];
            }
            float a0 = 0.f, a1 = 0.f, a2 = 0.f, a3 = 0.f, ax = 0.f;
#pragma unroll
            for (int t = 0; t < 8; ++t)
              if (b + t < Fprev) {
                float dvt = dv[b + t];
                a0 += rr[t].x * dvt; a1 += rr[t].y * dvt;
                a2 += rr[t].z * dvt; a3 += rr[t].w * dvt;
                ax += rx[t] * dvt;
              }
            i0 += (double)a0; i1 += (double)a1;
            i2 += (double)a2; i3 += (double)a3;
            if (isx) i4 += (double)ax;
          }
        }
        *(double2*)(field_lds + 4 * wid + 0) = make_double2(i0, i1);
        *(double2*)(field_lds + 4 * wid + 2) = make_double2(i2, i3);
        if (isx) field_lds[XBASE + wid] = i4;
      }
    } else {
      // ---- resolve chunk k: pure register chain, nothing memory-bound ahead ----
      double Ival = Ireg;
      float mcur = mym;
      float finals = 0.0f, finald = 0.0f;
      int conf = -1;
      bool locked = false;
      while (true) {
        float s = (Ival >= mt) ? 1.0f : -1.0f;   // I >= atanh(r) <=> tanh(I) >= r
        float dl = s - mcur;
        unsigned long long mask = __ballot(dl != 0.0f) & 0xFFFFull;
        mask &= (~0ull) << (conf + 1);
        if (mask == 0) {
          if (!locked) { finals = s; finald = 0.0f; }
          break;
        }
        int f = (int)__builtin_ctzll(mask);      // wave-uniform
        if (!locked && t16 <= f) { finals = s; finald = dl; locked = true; }
        float dl_f = __int_as_float(__builtin_amdgcn_readlane(__float_as_int(dl), f));
        float s_f  = __int_as_float(__builtin_amdgcn_readlane(__float_as_int(s), f));
        int   i_f  = __builtin_amdgcn_readlane(mi, f);
        float xcol, xnx;                          // Scol[f], SXcol[f]; f uniform -> scalar branches
        switch (f) {
          case 0:  xcol = sA.x; xnx = xA.x; break;  case 1:  xcol = sA.y; xnx = xA.y; break;
          case 2:  xcol = sA.z; xnx = xA.z; break;  case 3:  xcol = sA.w; xnx = xA.w; break;
          case 4:  xcol = sB.x; xnx = xB.x; break;  case 5:  xcol = sB.y; xnx = xB.y; break;
          case 6:  xcol = sB.z; xnx = xB.z; break;  case 7:  xcol = sB.w; xnx = xB.w; break;
          case 8:  xcol = sC.x; xnx = xC.x; break;  case 9:  xcol = sC.y; xnx = xC.y; break;
          case 10: xcol = sC.z; xnx = xC.z; break;  case 11: xcol = sC.w; xnx = xC.w; break;
          case 12: xcol = sD.x; xnx = xD.x; break;  case 13: xcol = sD.y; xnx = xD.y; break;
          default: if (f == 14) { xcol = sD.z; xnx = xD.z; }
                   else         { xcol = sD.w; xnx = xD.w; } break;
        }
        Ival += (double)(xcol * dl_f);            // exact product: dl in {-2,2}
        xacc += (double)(xnx * dl_f);             // cross-correction for chunk k+1, lane t16
        if (mi == i_f) mcur = s_f;                // in-chunk duplicate index
        conf = f;
      }
      // publish compacted flip list + m updates (last occurrence wins)
      unsigned long long fm = __ballot((tid < 16) && (finald != 0.0f));
      if (tid < 16) {
        if (finald != 0.0f) {
          int pos = __popcll(fm & ((1ull << t16) - 1ull));
          pubi_lds[cur][pos] = mi;
          pubd_lds[cur][pos] = finald;
        }
        if (mlo) m_lds[mi] = finals;
        if (tid == 0) pubF_lds[cur] = __popcll(fm);
      }
      __builtin_amdgcn_sched_barrier(0);   // keep memory pipeline below the resolve
      // store ST(k+1)/SX(k+1->k+2) (gathers issued one full iteration ago)
      ST_lds[(gq + 0) * SST + gt] = fST0;
      ST_lds[(gq + 1) * SST + gt] = fST1;
      ST_lds[(gq + 2) * SST + gt] = fST2;
      ST_lds[(gq + 3) * SST + gt] = fST3;
      SX_lds[(gq + 0) * SST + gt] = fSX0;
      SX_lds[(gq + 1) * SST + gt] = fSX1;
      SX_lds[(gq + 2) * SST + gt] = fSX2;
      SX_lds[(gq + 3) * SST + gt] = fSX3;
      // issue gathers for ST(k+2)/SX(k+2->k+3): addresses already in registers
      {
        const float* Jg = J + (size_t)gArow * N;
        fST0 = Jg[gAt0]; fST1 = Jg[gAt1]; fST2 = Jg[gAt2]; fST3 = Jg[gAt3];
        fSX0 = Jg[gAu0]; fSX1 = Jg[gAu1]; fSX2 = Jg[gAu2]; fSX3 = Jg[gAu3];
      }
      // issue next pipeline loads: chunk k+3 step data + gather-addr set gB
      {
        int b3 = k * CHUNK + 3 * CHUNK; if (b3 >= STEPS) b3 = 0;   // clamp: unused on tail
        int b4 = k * CHUNK + 4 * CHUNK; if (b4 >= STEPS) b4 = 0;
        int q3i = idx[b3 + t16];
        double q3t = thr[b3 + t16];
        int q3lo = lastocc[b3 + t16];
        int gBrow = idx[b3 + gt];
        int gBt0 = idx[b3 + gq];     int gBt1 = idx[b3 + gq + 1];
        int gBt2 = idx[b3 + gq + 2]; int gBt3 = idx[b3 + gq + 3];
        int gBu0 = idx[b4 + gq];     int gBu1 = idx[b4 + gq + 1];
        int gBu2 = idx[b4 + gq + 2]; int gBu3 = idx[b4 + gq + 3];
        // rotate pipeline registers (waits for these loads land at next iteration's uses)
        mi = ni;  mt = nt;  mlo = nlo;
        ni = p2i; nt = p2t; nlo = p2lo;
        p2i = q3i; p2t = q3t; p2lo = q3lo;
        gArow = gBrow;
        gAt0 = gBt0; gAt1 = gBt1; gAt2 = gBt2; gAt3 = gBt3;
        gAu0 = gBu0; gAu1 = gBu1; gAu2 = gBu2; gAu3 = gBu3;
      }
    }
    lgkm_barrier();
    // ================= Phase 2 (short) =================
    if (tid < 64) {
      // field_lds complete through chunk k-1; xacc supplies chunk k's terms
      Ireg = field_lds[mi] + xacc;   // mi = chunk k+1 index (rotated)
      mym = m_lds[mi];               // spins complete through chunk k
      xacc = 0.0;
      // prefetch ST/SX register fragments for chunk k+1 (stored this phase 1)
      const float* sp = &ST_lds[t16 * SST];
      sA = *(const float4*)(sp + 0);  sB = *(const float4*)(sp + 4);
      sC = *(const float4*)(sp + 8);  sD = *(const float4*)(sp + 12);
      const float* xp = &SX_lds[t16 * SST];
      xA = *(const float4*)(xp + 0);  xB = *(const float4*)(xp + 4);
      xC = *(const float4*)(xp + 8);  xD = *(const float4*)(xp + 12);
    } else {
      // pre-read chunk k's flip list so apply loads issue at next phase-1 entry
      Fprev = pubF_lds[cur];
      if (Fprev > 0) {
        int4 ra = *(const int4*)(pubi_lds[cur] + 0);
        int4 rb = *(const int4*)(pubi_lds[cur] + 4);
        int4 rc = *(const int4*)(pubi_lds[cur] + 8);
        int4 rd = *(const int4*)(pubi_lds[cur] + 12);
        float4 da = *(const float4*)(pubd_lds[cur] + 0);
        float4 db = *(const float4*)(pubd_lds[cur] + 4);
        float4 dc = *(const float4*)(pubd_lds[cur] + 8);
        float4 dd = *(const float4*)(pubd_lds[cur] + 12);
        rows[0] = ra.x;  rows[1] = ra.y;  rows[2] = ra.z;  rows[3] = ra.w;
        rows[4] = rb.x;  rows[5] = rb.y;  rows[6] = rb.z;  rows[7] = rb.w;
        rows[8] = rc.x;  rows[9] = rc.y;  rows[10] = rc.z; rows[11] = rc.w;
        rows[12] = rd.x; rows[13] = rd.y; rows[14] = rd.z; rows[15] = rd.w;
        dv[0] = da.x;  dv[1] = da.y;  dv[2] = da.z;  dv[3] = da.w;
        dv[4] = db.x;  dv[5] = db.y;  dv[6] = db.z;  dv[7] = db.w;
        dv[8] = dc.x;  dv[9] = dc.y;  dv[10] = dc.z; dv[11] = dc.w;
        dv[12] = dd.x; dv[13] = dd.y; dv[14] = dd.z; dv[15] = dd.w;
      }
    }
    lgkm_barrier();
    cur ^= 1;
  }

  __syncthreads();
  ((float4*)out)[tid] = ((const float4*)m_lds)[tid];
}

extern "C" void kernel_launch(void* const* d_in, const int* in_sizes, int n_in,
                              void* d_out, int out_size, void* d_ws, size_t ws_size,
                              hipStream_t stream) {
  const float* J = (const float*)d_in[0];
  const float* h = (const float*)d_in[1];
  const float* m0 = (const float*)d_in[2];
  const int* idx = (const int*)d_in[3];
  const float* u = (const float*)d_in[4];
  float* out = (float*)d_out;

  double* thr = (double*)d_ws;                                        // 16384 f64
  double* I0 = (double*)((char*)d_ws + STEPS * sizeof(double));       // 4096 f64
  int* lastocc = (int*)((char*)d_ws + STEPS * sizeof(double)
                                    + N * sizeof(double));            // 16384 i32

  pre_kernel<<<dim3(STEPS / 256), dim3(256), 0, stream>>>(u, idx, thr, lastocc);
  init_field_kernel<<<dim3(N), dim3(256), 0, stream>>>(J, h, m0, I0);
  pbit_kernel<<<dim3(1), dim3(MBLK), 0, stream>>>(J, m0, idx, thr, lastocc, I0, out);
}

// Round 3
// 1954.953 us; speedup vs baseline: 3.7087x; 3.7087x over previous
//
#include <hip/hip_runtime.h>
#include <math.h>

#define N 4096
#define STEPS 16384
#define WIN 32                 // steps resolved per barrier pair
#define NWIN (STEPS / WIN)
#define MBLK 1024
#define SBS 36   // padded stride (floats) for the 32x32 coupling block (float4-aligned)

// Workgroup barrier that does NOT drain vmcnt (LDS-only ordering between phases).
__device__ __forceinline__ void lgkm_barrier() {
  asm volatile("s_waitcnt lgkmcnt(0)\n\ts_barrier" ::: "memory");
}

// ---- prep: thr[t] = atanh(2u-1) in fp64; lastocc[t] = no later same-idx in window ----
__global__ __launch_bounds__(256) void pre_kernel(const float* __restrict__ u,
                                                  const int* __restrict__ idx,
                                                  double* __restrict__ thr,
                                                  int* __restrict__ lastocc) {
  int t = blockIdx.x * 256 + threadIdx.x;
  if (t < STEPS) {
    float r = 2.0f * u[t] - 1.0f;          // exact same fp32 rounding as reference
    double rd = (double)r;
    thr[t] = 0.5 * log((1.0 + rd) / (1.0 - rd));   // r=-1 -> -inf (tie->+1 matches ref)
    int cbase = t & ~(WIN - 1);
    int my = idx[t];
    int lo = 1;
    for (int tt = (t & (WIN - 1)) + 1; tt < WIN; ++tt)
      if (idx[cbase + tt] == my) { lo = 0; break; }
    lastocc[t] = lo;
  }
}

// ---- initial field: I0[row] = sum_k J[row,k]*m0[k] + h[row], fp64 accumulate ----
__global__ __launch_bounds__(256) void init_field_kernel(const float* __restrict__ J,
                                                         const float* __restrict__ h,
                                                         const float* __restrict__ m0,
                                                         double* __restrict__ I) {
  __shared__ double red[256];
  int row = blockIdx.x;
  const float4* Jr = (const float4*)(J + (size_t)row * N);
  const float4* mv = (const float4*)m0;
  double acc = 0.0;
  for (int q = threadIdx.x; q < N / 4; q += 256) {
    float4 a = Jr[q];
    float4 b = mv[q];
    acc += (double)(a.x * b.x) + (double)(a.y * b.y) +
           (double)(a.z * b.z) + (double)(a.w * b.w);
  }
  red[threadIdx.x] = acc;
  __syncthreads();
  for (int s = 128; s > 0; s >>= 1) {
    if (threadIdx.x < s) red[threadIdx.x] += red[threadIdx.x + s];
    __syncthreads();
  }
  if (threadIdx.x == 0) I[row] = red[0] + (double)h[row];
}

// ---- window-resolved Glauber chain: 1 workgroup, 1024 threads, WIN=32 ----
// Round-0 serial structure (proven fastest regime), window widened 16->32:
//   P1: wave0 resolves 32 steps flip-driven with the 32x32 coupling block
//       register-resident (8 float4/lane, J symmetric: one gather covers it);
//       publishes a compacted flip list. Workers park at the barrier.
//   P2: all 1024 threads apply the F flipped rows (uniform branches), fp64
//       register field + LDS write-through. Barriers are lgkm-only.
// Halves barrier pairs, apply invocations, and field read round-trips vs WIN=16.
__global__ __launch_bounds__(MBLK) void pbit_kernel(const float* __restrict__ J,
                                                    const float* __restrict__ m0,
                                                    const int* __restrict__ idx,
                                                    const double* __restrict__ thr,
                                                    const int* __restrict__ lastocc,
                                                    const double* __restrict__ I0,
                                                    float* __restrict__ out) {
  __shared__ __align__(16) double field_lds[N];        // 32 KB master field
  __shared__ __align__(16) float m_lds[N];             // 16 KB spins
  __shared__ __align__(16) float ST_lds[WIN * SBS];    // ST[r*SBS+c] = J[idx[r]][idx[c]] (sym)
  __shared__ __align__(16) int   pubi_lds[WIN];        // compacted flip rows
  __shared__ __align__(16) float pubd_lds[WIN];        // compacted deltas (+/-2)
  __shared__ int pubF_lds;                             // flip count

  const int tid = threadIdx.x;

  // owned field elements 4*tid..4*tid+3: fp64 registers + LDS write-through
  double i0, i1, i2, i3;
  {
    const double* ip = I0 + 4 * tid;
    i0 = ip[0]; i1 = ip[1]; i2 = ip[2]; i3 = ip[3];
    *(double2*)(field_lds + 4 * tid + 0) = make_double2(i0, i1);
    *(double2*)(field_lds + 4 * tid + 2) = make_double2(i2, i3);
  }
  ((float4*)m_lds)[tid] = ((const float4*)m0)[tid];

  const int t32 = tid & 31;      // step slot within window (lanes 32-63 duplicate)
  const int jrow = tid >> 1;     // gather row slot (wave0: 0..31)
  const int half = (tid & 1) * 16;  // gather col half

  // wave0 step-data pipeline (2 windows deep)
  int mi = 0, ni = 0, mlo = 0, nlo = 0;
  double mt = 0.0, nt = 0.0;

  if (tid < 64) {
    mi = idx[t32];       mt = thr[t32];       mlo = lastocc[t32];
    ni = idx[WIN + t32]; nt = thr[WIN + t32]; nlo = lastocc[WIN + t32];
    // synchronous 32x32 block gather for window 0 (addrs via shfl from mi)
    int r0 = __shfl(mi, jrow);
    const float* Jr = J + (size_t)r0 * N;
#pragma unroll
    for (int q = 0; q < 16; ++q) {
      int c = __shfl(mi, half + q);
      ST_lds[jrow * SBS + half + q] = Jr[c];
    }
  }
  __syncthreads();

  for (int k = 0; k < NWIN; ++k) {
    // ---------------- P1: wave0 resolves 32 steps ----------------
    if (tid < 64) {
      // issue block gather for window k+1 (addrs via shfl from ni; stored after resolve)
      int growv = __shfl(ni, jrow);
      const float* Jg = J + (size_t)growv * N;
      int gc0  = __shfl(ni, half + 0),  gc1  = __shfl(ni, half + 1);
      int gc2  = __shfl(ni, half + 2),  gc3  = __shfl(ni, half + 3);
      int gc4  = __shfl(ni, half + 4),  gc5  = __shfl(ni, half + 5);
      int gc6  = __shfl(ni, half + 6),  gc7  = __shfl(ni, half + 7);
      int gc8  = __shfl(ni, half + 8),  gc9  = __shfl(ni, half + 9);
      int gc10 = __shfl(ni, half + 10), gc11 = __shfl(ni, half + 11);
      int gc12 = __shfl(ni, half + 12), gc13 = __shfl(ni, half + 13);
      int gc14 = __shfl(ni, half + 14), gc15 = __shfl(ni, half + 15);
      float gv0  = Jg[gc0],  gv1  = Jg[gc1],  gv2  = Jg[gc2],  gv3  = Jg[gc3];
      float gv4  = Jg[gc4],  gv5  = Jg[gc5],  gv6  = Jg[gc6],  gv7  = Jg[gc7];
      float gv8  = Jg[gc8],  gv9  = Jg[gc9],  gv10 = Jg[gc10], gv11 = Jg[gc11];
      float gv12 = Jg[gc12], gv13 = Jg[gc13], gv14 = Jg[gc14], gv15 = Jg[gc15];
      // issue step-data loads for window k+2
      int b2 = (k + 2) * WIN; if (b2 >= STEPS) b2 = 0;   // clamp: unused on tail
      int n2i = idx[b2 + t32];
      double n2t = thr[b2 + t32];
      int n2lo = lastocc[b2 + t32];
      // this window's coupling column, register-resident:
      // lane j needs Scol[f] = J[idx[f]][idx[j]] = ST[j*SBS+f] (symmetry)
      const float* sp = &ST_lds[(size_t)t32 * SBS];
      float4 s0 = *(const float4*)(sp + 0),  s1 = *(const float4*)(sp + 4);
      float4 s2 = *(const float4*)(sp + 8),  s3 = *(const float4*)(sp + 12);
      float4 s4 = *(const float4*)(sp + 16), s5 = *(const float4*)(sp + 20);
      float4 s6 = *(const float4*)(sp + 24), s7 = *(const float4*)(sp + 28);
      double Ival = field_lds[mi];
      float mcur = m_lds[mi];
      float finals = 0.0f, finald = 0.0f;
      int conf = -1;
      bool locked = false;
      // flip-driven resolve: rounds = flips + 1, no LDS on the chain
      while (true) {
        float s = (Ival >= mt) ? 1.0f : -1.0f;   // I >= atanh(r) <=> tanh(I) >= r
        float dl = s - mcur;
        unsigned long long mask = __ballot(dl != 0.0f) & 0xFFFFFFFFull;
        mask &= (~0ull) << (conf + 1);
        if (mask == 0) {
          if (!locked) { finals = s; finald = 0.0f; }
          break;
        }
        int f = (int)__builtin_ctzll(mask);      // wave-uniform
        if (!locked && t32 <= f) { finals = s; finald = dl; locked = true; }
        float dl_f = __int_as_float(__builtin_amdgcn_readlane(__float_as_int(dl), f));
        float s_f  = __int_as_float(__builtin_amdgcn_readlane(__float_as_int(s), f));
        int   i_f  = __builtin_amdgcn_readlane(mi, f);
        float4 sel;                               // f uniform -> scalar branches
        switch (f >> 2) {
          case 0: sel = s0; break; case 1: sel = s1; break;
          case 2: sel = s2; break; case 3: sel = s3; break;
          case 4: sel = s4; break; case 5: sel = s5; break;
          case 6: sel = s6; break; default: sel = s7; break;
        }
        float xcol;
        switch (f & 3) {
          case 0: xcol = sel.x; break; case 1: xcol = sel.y; break;
          case 2: xcol = sel.z; break; default: xcol = sel.w; break;
        }
        Ival += (double)(xcol * dl_f);            // exact product: dl in {-2,2}
        if (mi == i_f) mcur = s_f;                // in-window duplicate index
        conf = f;
      }
      // publish: compacted flip list + m updates (last occurrence wins)
      unsigned long long fm = __ballot((tid < WIN) && (finald != 0.0f));
      if (tid < WIN) {
        if (finald != 0.0f) {
          int pos = __popcll(fm & ((1ull << t32) - 1ull));
          pubi_lds[pos] = mi;
          pubd_lds[pos] = finald;
        }
        if (mlo) m_lds[mi] = finals;
        if (tid == 0) pubF_lds = (int)__popcll(fm);
      }
      // store block for window k+1 (gather waited here, ~resolve-length slack)
      {
        float* dst = &ST_lds[jrow * SBS + half];
        *(float4*)(dst + 0)  = make_float4(gv0, gv1, gv2, gv3);
        *(float4*)(dst + 4)  = make_float4(gv4, gv5, gv6, gv7);
        *(float4*)(dst + 8)  = make_float4(gv8, gv9, gv10, gv11);
        *(float4*)(dst + 12) = make_float4(gv12, gv13, gv14, gv15);
      }
      // rotate step-data pipeline
      mi = ni;  mt = nt;  mlo = nlo;
      ni = n2i; nt = n2t; nlo = n2lo;
    }
    lgkm_barrier();

    // ---------------- P2: all threads apply the F flipped rows ----------------
    {
      int F = pubF_lds;
      if (F > 0) {                         // uniform: skip flip-free windows
        const float* Jb = J + 4 * (size_t)tid;
#pragma unroll
        for (int b = 0; b < WIN; b += 8) {
          if (b < F) {                     // uniform
            int4 r1 = *(const int4*)(pubi_lds + b);
            int4 r2 = *(const int4*)(pubi_lds + b + 4);
            float4 d1 = *(const float4*)(pubd_lds + b);
            float4 d2 = *(const float4*)(pubd_lds + b + 4);
            int rr[8] = {r1.x, r1.y, r1.z, r1.w, r2.x, r2.y, r2.z, r2.w};
            float dd[8] = {d1.x, d1.y, d1.z, d1.w, d2.x, d2.y, d2.z, d2.w};
            float4 rv[8];
            // loads first (back-to-back issue, one latency exposure per batch)
#pragma unroll
            for (int t = 0; t < 8; ++t)
              if (b + t < F) rv[t] = *(const float4*)(Jb + (size_t)rr[t] * N);
            float a0 = 0.f, a1 = 0.f, a2 = 0.f, a3 = 0.f;
#pragma unroll
            for (int t = 0; t < 8; ++t)
              if (b + t < F) {
                a0 += rv[t].x * dd[t]; a1 += rv[t].y * dd[t];
                a2 += rv[t].z * dd[t]; a3 += rv[t].w * dd[t];
              }
            // batch-local exact fp32 partials -> fp64 master
            i0 += (double)a0; i1 += (double)a1;
            i2 += (double)a2; i3 += (double)a3;
          }
        }
        *(double2*)(field_lds + 4 * tid + 0) = make_double2(i0, i1);
        *(double2*)(field_lds + 4 * tid + 2) = make_double2(i2, i3);
      }
    }
    lgkm_barrier();
  }

  __syncthreads();
  ((float4*)out)[tid] = ((const float4*)m_lds)[tid];
}

extern "C" void kernel_launch(void* const* d_in, const int* in_sizes, int n_in,
                              void* d_out, int out_size, void* d_ws, size_t ws_size,
                              hipStream_t stream) {
  const float* J = (const float*)d_in[0];
  const float* h = (const float*)d_in[1];
  const float* m0 = (const float*)d_in[2];
  const int* idx = (const int*)d_in[3];
  const float* u = (const float*)d_in[4];
  float* out = (float*)d_out;

  double* thr = (double*)d_ws;                                        // 16384 f64
  double* I0 = (double*)((char*)d_ws + STEPS * sizeof(double));       // 4096 f64
  int* lastocc = (int*)((char*)d_ws + STEPS * sizeof(double)
                                    + N * sizeof(double));            // 16384 i32

  pre_kernel<<<dim3(STEPS / 256), dim3(256), 0, stream>>>(u, idx, thr, lastocc);
  init_field_kernel<<<dim3(N), dim3(256), 0, stream>>>(J, h, m0, I0);
  pbit_kernel<<<dim3(1), dim3(MBLK), 0, stream>>>(J, m0, idx, thr, lastocc, I0, out);
}